// Round 7
// baseline (512.552 us; speedup 1.0000x reference)
//
#include <hip/hip_runtime.h>

#define N_NODES  100000
#define N_EDGES  3200000
#define NFEAT    256
#define NHID     128
#define NCLASS   16
#define TEXT_CNT 50000

#define RPB      256                          // rows per bucket
#define NB       ((N_NODES + RPB - 1) / RPB)  // 391 buckets
#define CAP      16384                        // fixed bucket capacity (2^14)
#define S_EPT    32                           // edges/thread, scatter pass
#define NBLKS    ((N_EDGES + 256 * S_EPT - 1) / (256 * S_EPT))  // 391

typedef unsigned int uint;
typedef __bf16 bf16x8 __attribute__((ext_vector_type(8)));
typedef __bf16 bf16x4 __attribute__((ext_vector_type(4)));
typedef float f32x4 __attribute__((ext_vector_type(4)));
typedef int i32x2 __attribute__((ext_vector_type(2)));

__device__ inline uint bf16_rne(float f) {
  uint u = __float_as_uint(f);
  return (u + 0x7fffu + ((u >> 16) & 1u)) >> 16;
}
__device__ inline float bf_lo(uint u) { return __uint_as_float(u << 16); }
__device__ inline float bf_hi(uint u) { return __uint_as_float(u & 0xffff0000u); }

// ---------------- fused prep: W1t, W2t, Wc1/2, bc1/2, cursor init ----------------

__global__ __launch_bounds__(256) void prep_kernel(const float* __restrict__ W1,
                                                   const float* __restrict__ W2,
                                                   const float* __restrict__ b2,
                                                   const float* __restrict__ cW1,
                                                   const float* __restrict__ cb1,
                                                   const float* __restrict__ cW2,
                                                   const float* __restrict__ cb2,
                                                   unsigned short* __restrict__ W1t,
                                                   unsigned short* __restrict__ W2t,
                                                   float* __restrict__ Wc1, float* __restrict__ bc1,
                                                   float* __restrict__ Wc2, float* __restrict__ bc2,
                                                   int* __restrict__ gcursor) {
  int idx = blockIdx.x * 256 + threadIdx.x;
  if (idx < 32768) {                       // W1t[n][k] = bf16(W1[k][n]), K=256,N=128
    int n = idx >> 8, k = idx & 255;
    W1t[idx] = (unsigned short)bf16_rne(W1[(size_t)k * NHID + n]);
  } else if (idx < 65536) {                // W2t[n][k] = bf16(W2[k][n]), K=128,N=256
    int i2 = idx - 32768;
    int n = i2 >> 7, k = i2 & 127;
    W2t[i2] = (unsigned short)bf16_rne(W2[(size_t)k * NFEAT + n]);
  } else if (idx < 69632) {                // Wc = W2 @ cW
    int e = idx - 65536;
    int set = e >> 11;
    int e2 = e & 2047;
    int i = e2 >> 4, c = e2 & 15;
    const float* cw = set ? cW2 : cW1;
    float acc = 0.f;
    for (int k = 0; k < NFEAT; ++k)
      acc += W2[(size_t)i * NFEAT + k] * cw[k * NCLASS + c];
    (set ? Wc2 : Wc1)[e2] = acc;
    if (e < 32) {
      int s2 = e >> 4, c2 = e & 15;
      const float* cwb = s2 ? cW2 : cW1;
      float b = (s2 ? cb2 : cb1)[c2];
      for (int k = 0; k < NFEAT; ++k) b += b2[k] * cwb[k * NCLASS + c2];
      (s2 ? bc2 : bc1)[c2] = b;
    }
  } else if (idx < 69632 + NB) {           // gcursor[b] = b*CAP
    int b = idx - 69632;
    gcursor[b] = b * CAP;
  }
}

// ---------------- multi-split scatter into fixed-capacity buckets ----------------
// packedA[p] = { (rowlocal<<17) | col , float_bits(val) }

__global__ __launch_bounds__(256) void bucket_scatter_kernel(const int* __restrict__ rows,
                                                             const int* __restrict__ cols,
                                                             const float* __restrict__ vals,
                                                             int* __restrict__ gcursor,
                                                             int2* __restrict__ packed, int E) {
  __shared__ int hist[NB];
  __shared__ int cur[NB];
  for (int i = threadIdx.x; i < NB; i += 256) hist[i] = 0;
  __syncthreads();
  int base = blockIdx.x * (256 * S_EPT);
#pragma unroll
  for (int i = 0; i < S_EPT; ++i) {
    int e = base + i * 256 + threadIdx.x;
    if (e < E) atomicAdd(&hist[__builtin_nontemporal_load(&rows[e]) >> 8], 1);
  }
  __syncthreads();
  for (int i = threadIdx.x; i < NB; i += 256) {
    int h = hist[i];
    cur[i] = h ? atomicAdd(&gcursor[i], h) : 0;
  }
  __syncthreads();
#pragma unroll
  for (int i = 0; i < S_EPT; ++i) {
    int e = base + i * 256 + threadIdx.x;
    if (e < E) {
      int r = __builtin_nontemporal_load(&rows[e]);
      int c = __builtin_nontemporal_load(&cols[e]);
      float v = __builtin_nontemporal_load(&vals[e]);
      int b = r >> 8;
      int p = atomicAdd(&cur[b], 1);
      if (p < ((b + 1) << 14))   // capacity guard
        packed[p] = make_int2(((r & 255) << 17) | c, __float_as_int(v));
    }
  }
}

// ---------------- scan bucket counts (from cursors) -> global CSR bases ----------------

__global__ __launch_bounds__(512) void bucket_scan_kernel(const int* __restrict__ gcursor,
                                                          int* __restrict__ bbase) {
  __shared__ int s[512];
  int t = threadIdx.x;
  int v = (t < NB) ? (gcursor[t] - t * CAP) : 0;
  s[t] = v;
  __syncthreads();
  for (int off = 1; off < 512; off <<= 1) {
    int u = (t >= off) ? s[t - off] : 0;
    __syncthreads();
    s[t] += u;
    __syncthreads();
  }
  if (t < NB) bbase[t] = s[t] - v;
  if (t == 0) bbase[NB] = N_EDGES;
}

// ---------------- per-bucket CSR finalize (512 threads) ----------------
// packedB[p] = { col<<8 (byte offset of feature row), float_bits(val) }

__global__ __launch_bounds__(512) void csr_finalize_kernel(const int* __restrict__ bbase,
                                                           const int2* __restrict__ packed_in,
                                                           int2* __restrict__ packed_out,
                                                           int* __restrict__ row_ptr) {
  __shared__ int hist[RPB];
  __shared__ int cur[RPB];
  int b = blockIdx.x;
  int s0 = b * CAP;
  int gout = bbase[b];
  int cnt = bbase[b + 1] - gout;
  int end = s0 + cnt;
  int t = threadIdx.x;
  const i32x2* pin = (const i32x2*)packed_in;
  if (t < RPB) hist[t] = 0;
  __syncthreads();
  {
    int i = s0 + t;
    for (; i + 1536 < end; i += 2048) {
      i32x2 a0 = __builtin_nontemporal_load(&pin[i]);
      i32x2 a1 = __builtin_nontemporal_load(&pin[i + 512]);
      i32x2 a2 = __builtin_nontemporal_load(&pin[i + 1024]);
      i32x2 a3 = __builtin_nontemporal_load(&pin[i + 1536]);
      atomicAdd(&hist[a0.x >> 17], 1);
      atomicAdd(&hist[a1.x >> 17], 1);
      atomicAdd(&hist[a2.x >> 17], 1);
      atomicAdd(&hist[a3.x >> 17], 1);
    }
    for (; i < end; i += 512) atomicAdd(&hist[__builtin_nontemporal_load(&pin[i]).x >> 17], 1);
  }
  __syncthreads();
  int v = (t < RPB) ? hist[t] : 0;
  if (t < RPB) cur[t] = v;
  __syncthreads();
  for (int off = 1; off < RPB; off <<= 1) {
    int u = (t >= off && t < RPB) ? cur[t - off] : 0;
    __syncthreads();
    if (t < RPB) cur[t] += u;
    __syncthreads();
  }
  if (t < RPB) {
    int rbase = gout + cur[t] - v;
    int row = b * RPB + t;
    if (row < N_NODES) row_ptr[row] = rbase;
    cur[t] = rbase;
  }
  if (b == 0 && t == 0) row_ptr[N_NODES] = N_EDGES;
  __syncthreads();
  {
    int i = s0 + t;
    for (; i + 1536 < end; i += 2048) {
      i32x2 a0 = __builtin_nontemporal_load(&pin[i]);
      i32x2 a1 = __builtin_nontemporal_load(&pin[i + 512]);
      i32x2 a2 = __builtin_nontemporal_load(&pin[i + 1024]);
      i32x2 a3 = __builtin_nontemporal_load(&pin[i + 1536]);
      int p0 = atomicAdd(&cur[a0.x >> 17], 1);
      int p1 = atomicAdd(&cur[a1.x >> 17], 1);
      int p2 = atomicAdd(&cur[a2.x >> 17], 1);
      int p3 = atomicAdd(&cur[a3.x >> 17], 1);
      packed_out[p0] = make_int2((a0.x & 0x1FFFF) << 8, a0.y);
      packed_out[p1] = make_int2((a1.x & 0x1FFFF) << 8, a1.y);
      packed_out[p2] = make_int2((a2.x & 0x1FFFF) << 8, a2.y);
      packed_out[p3] = make_int2((a3.x & 0x1FFFF) << 8, a3.y);
    }
    for (; i < end; i += 512) {
      i32x2 pk = __builtin_nontemporal_load(&pin[i]);
      int p = atomicAdd(&cur[pk.x >> 17], 1);
      packed_out[p] = make_int2((pk.x & 0x1FFFF) << 8, pk.y);
    }
  }
}

// ---------------- CSR SpMM over bf16 features, wave per row, 8B/lane pair-loads ----------------

__global__ __launch_bounds__(256) void spmm_bf16_kernel(const int* __restrict__ row_ptr,
                                                        const int2* __restrict__ packed,
                                                        const uint* __restrict__ src,   // [n][64] dwords
                                                        uint* __restrict__ dst,         // [n][64] dwords
                                                        const float* __restrict__ bias,
                                                        int relu, int nrows) {
  int tid = threadIdx.x;
  int lane = tid & 63;
  int half = lane >> 5;
  int l32 = lane & 31;
  int row = blockIdx.x * 4 + (tid >> 6);
  if (row >= nrows) return;
  int s = row_ptr[row];
  int e = row_ptr[row + 1];
  const char* srcb = (const char*)src + (l32 << 3);
  const i32x2* pk = (const i32x2*)packed;
  float a0 = 0.f, a1 = 0.f, a2 = 0.f, a3 = 0.f;
  int i = s;
  for (; i + 16 <= e; i += 16) {
    i32x2 m0 = __builtin_nontemporal_load(&pk[i + 0 + half]);
    i32x2 m1 = __builtin_nontemporal_load(&pk[i + 2 + half]);
    i32x2 m2 = __builtin_nontemporal_load(&pk[i + 4 + half]);
    i32x2 m3 = __builtin_nontemporal_load(&pk[i + 6 + half]);
    i32x2 m4 = __builtin_nontemporal_load(&pk[i + 8 + half]);
    i32x2 m5 = __builtin_nontemporal_load(&pk[i + 10 + half]);
    i32x2 m6 = __builtin_nontemporal_load(&pk[i + 12 + half]);
    i32x2 m7 = __builtin_nontemporal_load(&pk[i + 14 + half]);
    uint2 u0 = *(const uint2*)(srcb + (uint)m0.x);
    uint2 u1 = *(const uint2*)(srcb + (uint)m1.x);
    uint2 u2 = *(const uint2*)(srcb + (uint)m2.x);
    uint2 u3 = *(const uint2*)(srcb + (uint)m3.x);
    uint2 u4 = *(const uint2*)(srcb + (uint)m4.x);
    uint2 u5 = *(const uint2*)(srcb + (uint)m5.x);
    uint2 u6 = *(const uint2*)(srcb + (uint)m6.x);
    uint2 u7 = *(const uint2*)(srcb + (uint)m7.x);
    float v0 = __int_as_float(m0.y), v1 = __int_as_float(m1.y);
    float v2 = __int_as_float(m2.y), v3 = __int_as_float(m3.y);
    float v4 = __int_as_float(m4.y), v5 = __int_as_float(m5.y);
    float v6 = __int_as_float(m6.y), v7 = __int_as_float(m7.y);
    a0 += v0 * bf_lo(u0.x); a1 += v0 * bf_hi(u0.x); a2 += v0 * bf_lo(u0.y); a3 += v0 * bf_hi(u0.y);
    a0 += v1 * bf_lo(u1.x); a1 += v1 * bf_hi(u1.x); a2 += v1 * bf_lo(u1.y); a3 += v1 * bf_hi(u1.y);
    a0 += v2 * bf_lo(u2.x); a1 += v2 * bf_hi(u2.x); a2 += v2 * bf_lo(u2.y); a3 += v2 * bf_hi(u2.y);
    a0 += v3 * bf_lo(u3.x); a1 += v3 * bf_hi(u3.x); a2 += v3 * bf_lo(u3.y); a3 += v3 * bf_hi(u3.y);
    a0 += v4 * bf_lo(u4.x); a1 += v4 * bf_hi(u4.x); a2 += v4 * bf_lo(u4.y); a3 += v4 * bf_hi(u4.y);
    a0 += v5 * bf_lo(u5.x); a1 += v5 * bf_hi(u5.x); a2 += v5 * bf_lo(u5.y); a3 += v5 * bf_hi(u5.y);
    a0 += v6 * bf_lo(u6.x); a1 += v6 * bf_hi(u6.x); a2 += v6 * bf_lo(u6.y); a3 += v6 * bf_hi(u6.y);
    a0 += v7 * bf_lo(u7.x); a1 += v7 * bf_hi(u7.x); a2 += v7 * bf_lo(u7.y); a3 += v7 * bf_hi(u7.y);
  }
  for (; i + 8 <= e; i += 8) {
    i32x2 m0 = __builtin_nontemporal_load(&pk[i + 0 + half]);
    i32x2 m1 = __builtin_nontemporal_load(&pk[i + 2 + half]);
    i32x2 m2 = __builtin_nontemporal_load(&pk[i + 4 + half]);
    i32x2 m3 = __builtin_nontemporal_load(&pk[i + 6 + half]);
    uint2 u0 = *(const uint2*)(srcb + (uint)m0.x);
    uint2 u1 = *(const uint2*)(srcb + (uint)m1.x);
    uint2 u2 = *(const uint2*)(srcb + (uint)m2.x);
    uint2 u3 = *(const uint2*)(srcb + (uint)m3.x);
    float v0 = __int_as_float(m0.y), v1 = __int_as_float(m1.y);
    float v2 = __int_as_float(m2.y), v3 = __int_as_float(m3.y);
    a0 += v0 * bf_lo(u0.x); a1 += v0 * bf_hi(u0.x); a2 += v0 * bf_lo(u0.y); a3 += v0 * bf_hi(u0.y);
    a0 += v1 * bf_lo(u1.x); a1 += v1 * bf_hi(u1.x); a2 += v1 * bf_lo(u1.y); a3 += v1 * bf_hi(u1.y);
    a0 += v2 * bf_lo(u2.x); a1 += v2 * bf_hi(u2.x); a2 += v2 * bf_lo(u2.y); a3 += v2 * bf_hi(u2.y);
    a0 += v3 * bf_lo(u3.x); a1 += v3 * bf_hi(u3.x); a2 += v3 * bf_lo(u3.y); a3 += v3 * bf_hi(u3.y);
  }
  for (; i + 4 <= e; i += 4) {
    i32x2 m0 = __builtin_nontemporal_load(&pk[i + 0 + half]);
    i32x2 m1 = __builtin_nontemporal_load(&pk[i + 2 + half]);
    uint2 u0 = *(const uint2*)(srcb + (uint)m0.x);
    uint2 u1 = *(const uint2*)(srcb + (uint)m1.x);
    float v0 = __int_as_float(m0.y), v1 = __int_as_float(m1.y);
    a0 += v0 * bf_lo(u0.x); a1 += v0 * bf_hi(u0.x); a2 += v0 * bf_lo(u0.y); a3 += v0 * bf_hi(u0.y);
    a0 += v1 * bf_lo(u1.x); a1 += v1 * bf_hi(u1.x); a2 += v1 * bf_lo(u1.y); a3 += v1 * bf_hi(u1.y);
  }
  for (; i < e; i += 2) {
    int ee = i + half;
    int ok = ee < e;
    i32x2 m = pk[ok ? ee : (e - 1)];
    uint2 u = *(const uint2*)(srcb + (uint)m.x);
    float v = ok ? __int_as_float(m.y) : 0.f;
    a0 += v * bf_lo(u.x); a1 += v * bf_hi(u.x); a2 += v * bf_lo(u.y); a3 += v * bf_hi(u.y);
  }
  a0 += __shfl_xor(a0, 32); a1 += __shfl_xor(a1, 32);
  a2 += __shfl_xor(a2, 32); a3 += __shfl_xor(a3, 32);
  if (half == 0) {
    if (bias) {
      a0 += bias[4 * l32 + 0]; a1 += bias[4 * l32 + 1];
      a2 += bias[4 * l32 + 2]; a3 += bias[4 * l32 + 3];
    }
    if (relu) {
      a0 = fmaxf(a0, 0.f); a1 = fmaxf(a1, 0.f);
      a2 = fmaxf(a2, 0.f); a3 = fmaxf(a3, 0.f);
    }
    uint2 o;
    o.x = bf16_rne(a0) | (bf16_rne(a1) << 16);
    o.y = bf16_rne(a2) | (bf16_rne(a3) << 16);
    *(uint2*)&dst[(size_t)row * 64 + l32 * 2] = o;
  }
}

// ---------------- bf16 MFMA GEMM: C[M,N] = A[M,K] @ Bt^T (+bias) ----------------
// 128x128 tile, BK=32, 256 threads = 4 waves (2x2), 4x4 16x16x32 frags/wave.

template <int A_FP32, int OUT_BF16, int K, int N>
__global__ __launch_bounds__(256) void gemm_mfma_kernel(const void* __restrict__ Aptr,
                                                        const __bf16* __restrict__ Bt,  // [N][K]
                                                        const float* __restrict__ bias,
                                                        void* __restrict__ Cptr, int M) {
  __shared__ __bf16 As[128 * 40];
  __shared__ __bf16 Bs[128 * 40];
  int tid = threadIdx.x;
  int lane = tid & 63;
  int w = tid >> 6;
  int wr = w >> 1, wc = w & 1;
  int brow = blockIdx.x * 128;
  int bcol = blockIdx.y * 128;
  int r16 = lane & 15, kb = lane >> 4;

  f32x4 acc[4][4];
#pragma unroll
  for (int m = 0; m < 4; ++m)
#pragma unroll
    for (int n = 0; n < 4; ++n) acc[m][n] = (f32x4){0.f, 0.f, 0.f, 0.f};

  for (int k0 = 0; k0 < K; k0 += 32) {
    if (A_FP32) {
      const float* A = (const float*)Aptr;
#pragma unroll
      for (int i = 0; i < 4; ++i) {
        int idx = tid + i * 256;
        int row = idx >> 3;
        int kq = (idx & 7) << 2;
        int gr = brow + row;
        f32x4 v = (f32x4){0.f, 0.f, 0.f, 0.f};
        if (gr < M) v = __builtin_nontemporal_load((const f32x4*)&A[(size_t)gr * K + k0 + kq]);
        bf16x4 o;
        o[0] = (__bf16)v[0]; o[1] = (__bf16)v[1]; o[2] = (__bf16)v[2]; o[3] = (__bf16)v[3];
        *(bf16x4*)&As[row * 40 + kq] = o;
      }
    } else {
      const __bf16* A = (const __bf16*)Aptr;
#pragma unroll
      for (int i = 0; i < 2; ++i) {
        int idx = tid + i * 256;
        int row = idx >> 2;
        int kq = (idx & 3) << 3;
        int gr = brow + row;
        bf16x8 v = {};
        if (gr < M) v = *(const bf16x8*)&A[(size_t)gr * K + k0 + kq];
        *(bf16x8*)&As[row * 40 + kq] = v;
      }
    }
#pragma unroll
    for (int i = 0; i < 2; ++i) {
      int idx = tid + i * 256;
      int col = idx >> 2;
      int kq = (idx & 3) << 3;
      bf16x8 v = *(const bf16x8*)&Bt[(size_t)(bcol + col) * K + k0 + kq];
      *(bf16x8*)&Bs[col * 40 + kq] = v;
    }
    __syncthreads();

    bf16x8 a[4], b[4];
#pragma unroll
    for (int m = 0; m < 4; ++m)
      a[m] = *(bf16x8*)&As[(wr * 64 + m * 16 + r16) * 40 + kb * 8];
#pragma unroll
    for (int n = 0; n < 4; ++n)
      b[n] = *(bf16x8*)&Bs[(wc * 64 + n * 16 + r16) * 40 + kb * 8];
#pragma unroll
    for (int m = 0; m < 4; ++m)
#pragma unroll
      for (int n = 0; n < 4; ++n)
        acc[m][n] = __builtin_amdgcn_mfma_f32_16x16x32_bf16(a[m], b[n], acc[m][n], 0, 0, 0);
    __syncthreads();
  }

  int crow0 = brow + wr * 64;
  int ccol0 = bcol + wc * 64;
#pragma unroll
  for (int n = 0; n < 4; ++n) {
    int col = ccol0 + n * 16 + r16;
    float bv = bias ? bias[col] : 0.f;
#pragma unroll
    for (int m = 0; m < 4; ++m) {
#pragma unroll
      for (int r = 0; r < 4; ++r) {
        int row = crow0 + m * 16 + kb * 4 + r;
        if (row < M) {
          float val = acc[m][n][r] + bv;
          if (OUT_BF16)
            ((unsigned short*)Cptr)[(size_t)row * N + col] = (unsigned short)bf16_rne(val);
          else
            __builtin_nontemporal_store(val, &((float*)Cptr)[(size_t)row * N + col]);
        }
      }
    }
  }
}

// ---------------- classifier (both regions in one launch) ----------------

__global__ __launch_bounds__(256) void cls_kernel(const uint* __restrict__ t3,
                                                  const float* __restrict__ Wc1,
                                                  const float* __restrict__ bc1,
                                                  const float* __restrict__ Wc2,
                                                  const float* __restrict__ bc2,
                                                  float* __restrict__ out1,
                                                  float* __restrict__ out2) {
  int half = gridDim.x >> 1;
  int region = blockIdx.x >= half;
  int bid = region ? blockIdx.x - half : blockIdx.x;
  const float* Wc = region ? Wc2 : Wc1;
  const float* bc = region ? bc2 : bc1;
  float* outp = region ? out2 : out1;
  int row0 = region ? TEXT_CNT : 0;
  int nrows = region ? (N_NODES - TEXT_CNT) : TEXT_CNT;

  int lane = threadIdx.x & 63;
  int wav = bid * 4 + (threadIdx.x >> 6);
  int nw = half * 4;
  int c = lane & 15;
  int kg = lane >> 4;
  float w[32];
#pragma unroll
  for (int j = 0; j < 32; ++j) w[j] = Wc[(kg * 32 + j) * NCLASS + c];
  float bcv = bc[c];
  for (int r = wav; r < nrows; r += nw) {
    const uint4* rp = (const uint4*)&t3[(size_t)(row0 + r) * 64 + kg * 16];
    float acc = 0.f;
#pragma unroll
    for (int q = 0; q < 4; ++q) {
      uint4 u = rp[q];
      acc += bf_lo(u.x) * w[q * 8 + 0] + bf_hi(u.x) * w[q * 8 + 1]
           + bf_lo(u.y) * w[q * 8 + 2] + bf_hi(u.y) * w[q * 8 + 3]
           + bf_lo(u.z) * w[q * 8 + 4] + bf_hi(u.z) * w[q * 8 + 5]
           + bf_lo(u.w) * w[q * 8 + 6] + bf_hi(u.w) * w[q * 8 + 7];
    }
    acc += __shfl_xor(acc, 16);
    acc += __shfl_xor(acc, 32);
    if (lane < 16) outp[(size_t)r * NCLASS + lane] = acc + bcv;
  }
}

// ---------------- launch ----------------

extern "C" void kernel_launch(void* const* d_in, const int* in_sizes, int n_in,
                              void* d_out, int out_size, void* d_ws, size_t ws_size,
                              hipStream_t stream) {
  const float* x     = (const float*)d_in[0];
  const int*   arows = (const int*)d_in[1];
  const int*   acols = (const int*)d_in[2];
  const float* avals = (const float*)d_in[3];
  const float* W1    = (const float*)d_in[4];
  const float* b1    = (const float*)d_in[5];
  const float* W2    = (const float*)d_in[6];
  const float* b2    = (const float*)d_in[7];
  const float* cW1   = (const float*)d_in[8];
  const float* cb1   = (const float*)d_in[9];
  const float* cW2   = (const float*)d_in[10];
  const float* cb2   = (const float*)d_in[11];
  float* outp = (float*)d_out;

  char* ws = (char*)d_ws;
  size_t off = 0;
  auto alloc = [&](size_t bytes) -> void* {
    void* p = ws + off;
    off += (bytes + 255) & ~(size_t)255;
    return p;
  };
  uint*  t1u     = (uint*) alloc((size_t)N_NODES * 64 * 4);   // bf16 [N][128]
  uint*  hu      = (uint*) alloc((size_t)N_NODES * 64 * 4);   // bf16 [N][128]
  uint*  t3u     = (uint*) alloc((size_t)N_NODES * 64 * 4);   // bf16 [N][128]
  int2*  packedA = (int2*) alloc((size_t)NB * CAP * 8);       // fixed-cap buckets
  int2*  packedB = (int2*) alloc((size_t)N_EDGES * 8);        // row-grouped (CSR)
  int*   bbase   = (int*)  alloc((size_t)(NB + 1) * 4);
  int*   gcursor = (int*)  alloc((size_t)NB * 4);
  int*   rowp    = (int*)  alloc((size_t)(N_NODES + 1) * 4);
  unsigned short* W1t = (unsigned short*)alloc((size_t)NHID * NFEAT * 2);  // [128][256]
  unsigned short* W2t = (unsigned short*)alloc((size_t)NFEAT * NHID * 2);  // [256][128]
  float* Wc1     = (float*)alloc(NHID * NCLASS * 4);
  float* Wc2     = (float*)alloc(NHID * NCLASS * 4);
  float* bc1     = (float*)alloc(64);
  float* bc2     = (float*)alloc(64);

  // ---- 1. fused prep (weights + cursors) ----
  prep_kernel<<<(69632 + NB + 255) / 256, 256, 0, stream>>>(
      W1, W2, b2, cW1, cb1, cW2, cb2, W1t, W2t, Wc1, bc1, Wc2, bc2, gcursor);

  // ---- 2. bucket scatter ----
  bucket_scatter_kernel<<<NBLKS, 256, 0, stream>>>(arows, acols, avals, gcursor, packedA, N_EDGES);

  // ---- 3-4. scan + finalize ----
  bucket_scan_kernel<<<1, 512, 0, stream>>>(gcursor, bbase);
  csr_finalize_kernel<<<NB, 512, 0, stream>>>(bbase, packedA, packedB, rowp);

  // ---- 5. t1 = bf16(x @ W1) ----
  int mblk = (N_NODES + 127) / 128;  // 782
  gemm_mfma_kernel<1, 1, NFEAT, NHID><<<dim3(mblk, 1), 256, 0, stream>>>(
      x, (const __bf16*)W1t, nullptr, t1u, N_NODES);
  // ---- 6. h = bf16(relu(A @ t1 + b1)) ----
  spmm_bf16_kernel<<<(N_NODES + 3) / 4, 256, 0, stream>>>(rowp, packedB, t1u, hu, b1, 1, N_NODES);
  // ---- 7. t3 = bf16(A @ h) ----
  spmm_bf16_kernel<<<(N_NODES + 3) / 4, 256, 0, stream>>>(rowp, packedB, hu, t3u, nullptr, 0, N_NODES);
  // ---- 8. out = t3 @ W2 + b2 (fp32 out, NT stores) ----
  gemm_mfma_kernel<0, 0, NHID, NFEAT><<<dim3(mblk, 2), 256, 0, stream>>>(
      t3u, (const __bf16*)W2t, b2, outp, N_NODES);
  // ---- 9. classifiers ----
  cls_kernel<<<2048, 256, 0, stream>>>(t3u, Wc1, bc1, Wc2, bc2,
      outp + (size_t)N_NODES * NFEAT,
      outp + (size_t)N_NODES * NFEAT + (size_t)TEXT_CNT * NCLASS);
}

// Round 8
// 478.917 us; speedup vs baseline: 1.0702x; 1.0702x over previous
//
#include <hip/hip_runtime.h>

#define N_NODES  100000
#define N_EDGES  3200000
#define NFEAT    256
#define NHID     128
#define NCLASS   16
#define TEXT_CNT 50000

#define RPB      256                          // rows per bucket
#define NB       ((N_NODES + RPB - 1) / RPB)  // 391 buckets
#define CAP      16384                        // fixed bucket capacity (2^14)
#define S_EPT    32                           // edges/thread, scatter pass
#define NBLKS    ((N_EDGES + 256 * S_EPT - 1) / (256 * S_EPT))  // 391

typedef unsigned int uint;
typedef __bf16 bf16x8 __attribute__((ext_vector_type(8)));
typedef __bf16 bf16x4 __attribute__((ext_vector_type(4)));
typedef float f32x4 __attribute__((ext_vector_type(4)));

__device__ inline uint bf16_rne(float f) {
  uint u = __float_as_uint(f);
  return (u + 0x7fffu + ((u >> 16) & 1u)) >> 16;
}
__device__ inline float bf_lo(uint u) { return __uint_as_float(u << 16); }
__device__ inline float bf_hi(uint u) { return __uint_as_float(u & 0xffff0000u); }

// ---------------- fused prep: W1t, W2t, Wc1/2, bc1/2, cursor init ----------------

__global__ __launch_bounds__(256) void prep_kernel(const float* __restrict__ W1,
                                                   const float* __restrict__ W2,
                                                   const float* __restrict__ b2,
                                                   const float* __restrict__ cW1,
                                                   const float* __restrict__ cb1,
                                                   const float* __restrict__ cW2,
                                                   const float* __restrict__ cb2,
                                                   unsigned short* __restrict__ W1t,
                                                   unsigned short* __restrict__ W2t,
                                                   float* __restrict__ Wc1, float* __restrict__ bc1,
                                                   float* __restrict__ Wc2, float* __restrict__ bc2,
                                                   int* __restrict__ gcursor) {
  int idx = blockIdx.x * 256 + threadIdx.x;
  if (idx < 32768) {                       // W1t[n][k] = bf16(W1[k][n]), K=256,N=128
    int n = idx >> 8, k = idx & 255;
    W1t[idx] = (unsigned short)bf16_rne(W1[(size_t)k * NHID + n]);
  } else if (idx < 65536) {                // W2t[n][k] = bf16(W2[k][n]), K=128,N=256
    int i2 = idx - 32768;
    int n = i2 >> 7, k = i2 & 127;
    W2t[i2] = (unsigned short)bf16_rne(W2[(size_t)k * NFEAT + n]);
  } else if (idx < 69632) {                // Wc = W2 @ cW
    int e = idx - 65536;
    int set = e >> 11;
    int e2 = e & 2047;
    int i = e2 >> 4, c = e2 & 15;
    const float* cw = set ? cW2 : cW1;
    float acc = 0.f;
    for (int k = 0; k < NFEAT; ++k)
      acc += W2[(size_t)i * NFEAT + k] * cw[k * NCLASS + c];
    (set ? Wc2 : Wc1)[e2] = acc;
    if (e < 32) {
      int s2 = e >> 4, c2 = e & 15;
      const float* cwb = s2 ? cW2 : cW1;
      float b = (s2 ? cb2 : cb1)[c2];
      for (int k = 0; k < NFEAT; ++k) b += b2[k] * cwb[k * NCLASS + c2];
      (s2 ? bc2 : bc1)[c2] = b;
    }
  } else if (idx < 69632 + NB) {           // gcursor[b] = b*CAP
    int b = idx - 69632;
    gcursor[b] = b * CAP;
  }
}

// ---------------- multi-split scatter into fixed-capacity buckets ----------------
// packedA[p] = { (rowlocal<<17) | col , float_bits(val) }

__global__ __launch_bounds__(256) void bucket_scatter_kernel(const int* __restrict__ rows,
                                                             const int* __restrict__ cols,
                                                             const float* __restrict__ vals,
                                                             int* __restrict__ gcursor,
                                                             int2* __restrict__ packed, int E) {
  __shared__ int hist[NB];
  __shared__ int cur[NB];
  for (int i = threadIdx.x; i < NB; i += 256) hist[i] = 0;
  __syncthreads();
  int base = blockIdx.x * (256 * S_EPT);
#pragma unroll
  for (int i = 0; i < S_EPT; ++i) {
    int e = base + i * 256 + threadIdx.x;
    if (e < E) atomicAdd(&hist[rows[e] >> 8], 1);
  }
  __syncthreads();
  for (int i = threadIdx.x; i < NB; i += 256) {
    int h = hist[i];
    cur[i] = h ? atomicAdd(&gcursor[i], h) : 0;
  }
  __syncthreads();
#pragma unroll
  for (int i = 0; i < S_EPT; ++i) {
    int e = base + i * 256 + threadIdx.x;
    if (e < E) {
      int r = rows[e];
      int b = r >> 8;
      int p = atomicAdd(&cur[b], 1);
      if (p < ((b + 1) << 14))   // capacity guard
        packed[p] = make_int2(((r & 255) << 17) | cols[e], __float_as_int(vals[e]));
    }
  }
}

// ---------------- scan bucket counts (from cursors) -> global CSR bases ----------------

__global__ __launch_bounds__(512) void bucket_scan_kernel(const int* __restrict__ gcursor,
                                                          int* __restrict__ bbase) {
  __shared__ int s[512];
  int t = threadIdx.x;
  int v = (t < NB) ? (gcursor[t] - t * CAP) : 0;
  s[t] = v;
  __syncthreads();
  for (int off = 1; off < 512; off <<= 1) {
    int u = (t >= off) ? s[t - off] : 0;
    __syncthreads();
    s[t] += u;
    __syncthreads();
  }
  if (t < NB) bbase[t] = s[t] - v;
  if (t == 0) bbase[NB] = N_EDGES;
}

// ---------------- per-bucket CSR finalize (512 threads) ----------------
// packedB[p] = { col<<8 (byte offset of feature row), float_bits(val) }

__global__ __launch_bounds__(512) void csr_finalize_kernel(const int* __restrict__ bbase,
                                                           const int2* __restrict__ packed_in,
                                                           int2* __restrict__ packed_out,
                                                           int* __restrict__ row_ptr) {
  __shared__ int hist[RPB];
  __shared__ int cur[RPB];
  int b = blockIdx.x;
  int s0 = b * CAP;
  int gout = bbase[b];
  int cnt = bbase[b + 1] - gout;
  int end = s0 + cnt;
  int t = threadIdx.x;
  if (t < RPB) hist[t] = 0;
  __syncthreads();
  {
    int i = s0 + t;
    for (; i + 1536 < end; i += 2048) {
      int2 a0 = packed_in[i], a1 = packed_in[i + 512];
      int2 a2 = packed_in[i + 1024], a3 = packed_in[i + 1536];
      atomicAdd(&hist[a0.x >> 17], 1);
      atomicAdd(&hist[a1.x >> 17], 1);
      atomicAdd(&hist[a2.x >> 17], 1);
      atomicAdd(&hist[a3.x >> 17], 1);
    }
    for (; i < end; i += 512) atomicAdd(&hist[packed_in[i].x >> 17], 1);
  }
  __syncthreads();
  int v = (t < RPB) ? hist[t] : 0;
  if (t < RPB) cur[t] = v;
  __syncthreads();
  for (int off = 1; off < RPB; off <<= 1) {
    int u = (t >= off && t < RPB) ? cur[t - off] : 0;
    __syncthreads();
    if (t < RPB) cur[t] += u;
    __syncthreads();
  }
  if (t < RPB) {
    int rbase = gout + cur[t] - v;
    int row = b * RPB + t;
    if (row < N_NODES) row_ptr[row] = rbase;
    cur[t] = rbase;
  }
  if (b == 0 && t == 0) row_ptr[N_NODES] = N_EDGES;
  __syncthreads();
  {
    int i = s0 + t;
    for (; i + 1536 < end; i += 2048) {
      int2 a0 = packed_in[i], a1 = packed_in[i + 512];
      int2 a2 = packed_in[i + 1024], a3 = packed_in[i + 1536];
      int p0 = atomicAdd(&cur[a0.x >> 17], 1);
      int p1 = atomicAdd(&cur[a1.x >> 17], 1);
      int p2 = atomicAdd(&cur[a2.x >> 17], 1);
      int p3 = atomicAdd(&cur[a3.x >> 17], 1);
      packed_out[p0] = make_int2((a0.x & 0x1FFFF) << 8, a0.y);
      packed_out[p1] = make_int2((a1.x & 0x1FFFF) << 8, a1.y);
      packed_out[p2] = make_int2((a2.x & 0x1FFFF) << 8, a2.y);
      packed_out[p3] = make_int2((a3.x & 0x1FFFF) << 8, a3.y);
    }
    for (; i < end; i += 512) {
      int2 pk = packed_in[i];
      int p = atomicAdd(&cur[pk.x >> 17], 1);
      packed_out[p] = make_int2((pk.x & 0x1FFFF) << 8, pk.y);
    }
  }
}

// ---------------- CSR SpMM over bf16 features, wave per row, 8B/lane pair-loads ----------------

__global__ __launch_bounds__(256) void spmm_bf16_kernel(const int* __restrict__ row_ptr,
                                                        const int2* __restrict__ packed,
                                                        const uint* __restrict__ src,   // [n][64] dwords
                                                        uint* __restrict__ dst,         // [n][64] dwords
                                                        const float* __restrict__ bias,
                                                        int relu, int nrows) {
  int tid = threadIdx.x;
  int lane = tid & 63;
  int half = lane >> 5;
  int l32 = lane & 31;
  int row = blockIdx.x * 4 + (tid >> 6);
  if (row >= nrows) return;
  int s = row_ptr[row];
  int e = row_ptr[row + 1];
  const char* srcb = (const char*)src + (l32 << 3);
  float a0 = 0.f, a1 = 0.f, a2 = 0.f, a3 = 0.f;
  int i = s;
  for (; i + 16 <= e; i += 16) {
    int2 m0 = packed[i + 0 + half], m1 = packed[i + 2 + half];
    int2 m2 = packed[i + 4 + half], m3 = packed[i + 6 + half];
    int2 m4 = packed[i + 8 + half], m5 = packed[i + 10 + half];
    int2 m6 = packed[i + 12 + half], m7 = packed[i + 14 + half];
    uint2 u0 = *(const uint2*)(srcb + (uint)m0.x);
    uint2 u1 = *(const uint2*)(srcb + (uint)m1.x);
    uint2 u2 = *(const uint2*)(srcb + (uint)m2.x);
    uint2 u3 = *(const uint2*)(srcb + (uint)m3.x);
    uint2 u4 = *(const uint2*)(srcb + (uint)m4.x);
    uint2 u5 = *(const uint2*)(srcb + (uint)m5.x);
    uint2 u6 = *(const uint2*)(srcb + (uint)m6.x);
    uint2 u7 = *(const uint2*)(srcb + (uint)m7.x);
    float v0 = __int_as_float(m0.y), v1 = __int_as_float(m1.y);
    float v2 = __int_as_float(m2.y), v3 = __int_as_float(m3.y);
    float v4 = __int_as_float(m4.y), v5 = __int_as_float(m5.y);
    float v6 = __int_as_float(m6.y), v7 = __int_as_float(m7.y);
    a0 += v0 * bf_lo(u0.x); a1 += v0 * bf_hi(u0.x); a2 += v0 * bf_lo(u0.y); a3 += v0 * bf_hi(u0.y);
    a0 += v1 * bf_lo(u1.x); a1 += v1 * bf_hi(u1.x); a2 += v1 * bf_lo(u1.y); a3 += v1 * bf_hi(u1.y);
    a0 += v2 * bf_lo(u2.x); a1 += v2 * bf_hi(u2.x); a2 += v2 * bf_lo(u2.y); a3 += v2 * bf_hi(u2.y);
    a0 += v3 * bf_lo(u3.x); a1 += v3 * bf_hi(u3.x); a2 += v3 * bf_lo(u3.y); a3 += v3 * bf_hi(u3.y);
    a0 += v4 * bf_lo(u4.x); a1 += v4 * bf_hi(u4.x); a2 += v4 * bf_lo(u4.y); a3 += v4 * bf_hi(u4.y);
    a0 += v5 * bf_lo(u5.x); a1 += v5 * bf_hi(u5.x); a2 += v5 * bf_lo(u5.y); a3 += v5 * bf_hi(u5.y);
    a0 += v6 * bf_lo(u6.x); a1 += v6 * bf_hi(u6.x); a2 += v6 * bf_lo(u6.y); a3 += v6 * bf_hi(u6.y);
    a0 += v7 * bf_lo(u7.x); a1 += v7 * bf_hi(u7.x); a2 += v7 * bf_lo(u7.y); a3 += v7 * bf_hi(u7.y);
  }
  for (; i + 8 <= e; i += 8) {
    int2 m0 = packed[i + 0 + half], m1 = packed[i + 2 + half];
    int2 m2 = packed[i + 4 + half], m3 = packed[i + 6 + half];
    uint2 u0 = *(const uint2*)(srcb + (uint)m0.x);
    uint2 u1 = *(const uint2*)(srcb + (uint)m1.x);
    uint2 u2 = *(const uint2*)(srcb + (uint)m2.x);
    uint2 u3 = *(const uint2*)(srcb + (uint)m3.x);
    float v0 = __int_as_float(m0.y), v1 = __int_as_float(m1.y);
    float v2 = __int_as_float(m2.y), v3 = __int_as_float(m3.y);
    a0 += v0 * bf_lo(u0.x); a1 += v0 * bf_hi(u0.x); a2 += v0 * bf_lo(u0.y); a3 += v0 * bf_hi(u0.y);
    a0 += v1 * bf_lo(u1.x); a1 += v1 * bf_hi(u1.x); a2 += v1 * bf_lo(u1.y); a3 += v1 * bf_hi(u1.y);
    a0 += v2 * bf_lo(u2.x); a1 += v2 * bf_hi(u2.x); a2 += v2 * bf_lo(u2.y); a3 += v2 * bf_hi(u2.y);
    a0 += v3 * bf_lo(u3.x); a1 += v3 * bf_hi(u3.x); a2 += v3 * bf_lo(u3.y); a3 += v3 * bf_hi(u3.y);
  }
  for (; i + 4 <= e; i += 4) {
    int2 m0 = packed[i + 0 + half], m1 = packed[i + 2 + half];
    uint2 u0 = *(const uint2*)(srcb + (uint)m0.x);
    uint2 u1 = *(const uint2*)(srcb + (uint)m1.x);
    float v0 = __int_as_float(m0.y), v1 = __int_as_float(m1.y);
    a0 += v0 * bf_lo(u0.x); a1 += v0 * bf_hi(u0.x); a2 += v0 * bf_lo(u0.y); a3 += v0 * bf_hi(u0.y);
    a0 += v1 * bf_lo(u1.x); a1 += v1 * bf_hi(u1.x); a2 += v1 * bf_lo(u1.y); a3 += v1 * bf_hi(u1.y);
  }
  for (; i < e; i += 2) {
    int ee = i + half;
    int ok = ee < e;
    int2 m = packed[ok ? ee : (e - 1)];
    uint2 u = *(const uint2*)(srcb + (uint)m.x);
    float v = ok ? __int_as_float(m.y) : 0.f;
    a0 += v * bf_lo(u.x); a1 += v * bf_hi(u.x); a2 += v * bf_lo(u.y); a3 += v * bf_hi(u.y);
  }
  a0 += __shfl_xor(a0, 32); a1 += __shfl_xor(a1, 32);
  a2 += __shfl_xor(a2, 32); a3 += __shfl_xor(a3, 32);
  if (half == 0) {
    if (bias) {
      a0 += bias[4 * l32 + 0]; a1 += bias[4 * l32 + 1];
      a2 += bias[4 * l32 + 2]; a3 += bias[4 * l32 + 3];
    }
    if (relu) {
      a0 = fmaxf(a0, 0.f); a1 = fmaxf(a1, 0.f);
      a2 = fmaxf(a2, 0.f); a3 = fmaxf(a3, 0.f);
    }
    uint2 o;
    o.x = bf16_rne(a0) | (bf16_rne(a1) << 16);
    o.y = bf16_rne(a2) | (bf16_rne(a3) << 16);
    *(uint2*)&dst[(size_t)row * 64 + l32 * 2] = o;
  }
}

// ---------------- bf16 MFMA GEMM: C[M,N] = A[M,K] @ Bt^T (+bias) ----------------
// 128x128 tile, BK=32, 256 threads = 4 waves (2x2), 4x4 16x16x32 frags/wave.

template <int A_FP32, int OUT_BF16, int K, int N>
__global__ __launch_bounds__(256) void gemm_mfma_kernel(const void* __restrict__ Aptr,
                                                        const __bf16* __restrict__ Bt,  // [N][K]
                                                        const float* __restrict__ bias,
                                                        void* __restrict__ Cptr, int M) {
  __shared__ __bf16 As[128 * 40];
  __shared__ __bf16 Bs[128 * 40];
  int tid = threadIdx.x;
  int lane = tid & 63;
  int w = tid >> 6;
  int wr = w >> 1, wc = w & 1;
  int brow = blockIdx.x * 128;
  int bcol = blockIdx.y * 128;
  int r16 = lane & 15, kb = lane >> 4;

  f32x4 acc[4][4];
#pragma unroll
  for (int m = 0; m < 4; ++m)
#pragma unroll
    for (int n = 0; n < 4; ++n) acc[m][n] = (f32x4){0.f, 0.f, 0.f, 0.f};

  for (int k0 = 0; k0 < K; k0 += 32) {
    if (A_FP32) {
      const float* A = (const float*)Aptr;
#pragma unroll
      for (int i = 0; i < 4; ++i) {
        int idx = tid + i * 256;
        int row = idx >> 3;
        int kq = (idx & 7) << 2;
        int gr = brow + row;
        float4 v = make_float4(0.f, 0.f, 0.f, 0.f);
        if (gr < M) v = *(const float4*)&A[(size_t)gr * K + k0 + kq];
        bf16x4 o;
        o[0] = (__bf16)v.x; o[1] = (__bf16)v.y; o[2] = (__bf16)v.z; o[3] = (__bf16)v.w;
        *(bf16x4*)&As[row * 40 + kq] = o;
      }
    } else {
      const __bf16* A = (const __bf16*)Aptr;
#pragma unroll
      for (int i = 0; i < 2; ++i) {
        int idx = tid + i * 256;
        int row = idx >> 2;
        int kq = (idx & 3) << 3;
        int gr = brow + row;
        bf16x8 v = {};
        if (gr < M) v = *(const bf16x8*)&A[(size_t)gr * K + k0 + kq];
        *(bf16x8*)&As[row * 40 + kq] = v;
      }
    }
#pragma unroll
    for (int i = 0; i < 2; ++i) {
      int idx = tid + i * 256;
      int col = idx >> 2;
      int kq = (idx & 3) << 3;
      bf16x8 v = *(const bf16x8*)&Bt[(size_t)(bcol + col) * K + k0 + kq];
      *(bf16x8*)&Bs[col * 40 + kq] = v;
    }
    __syncthreads();

    bf16x8 a[4], b[4];
#pragma unroll
    for (int m = 0; m < 4; ++m)
      a[m] = *(bf16x8*)&As[(wr * 64 + m * 16 + r16) * 40 + kb * 8];
#pragma unroll
    for (int n = 0; n < 4; ++n)
      b[n] = *(bf16x8*)&Bs[(wc * 64 + n * 16 + r16) * 40 + kb * 8];
#pragma unroll
    for (int m = 0; m < 4; ++m)
#pragma unroll
      for (int n = 0; n < 4; ++n)
        acc[m][n] = __builtin_amdgcn_mfma_f32_16x16x32_bf16(a[m], b[n], acc[m][n], 0, 0, 0);
    __syncthreads();
  }

  int crow0 = brow + wr * 64;
  int ccol0 = bcol + wc * 64;
#pragma unroll
  for (int n = 0; n < 4; ++n) {
    int col = ccol0 + n * 16 + r16;
    float bv = bias ? bias[col] : 0.f;
#pragma unroll
    for (int m = 0; m < 4; ++m) {
#pragma unroll
      for (int r = 0; r < 4; ++r) {
        int row = crow0 + m * 16 + kb * 4 + r;
        if (row < M) {
          float val = acc[m][n][r] + bv;
          if (OUT_BF16)
            ((unsigned short*)Cptr)[(size_t)row * N + col] = (unsigned short)bf16_rne(val);
          else
            ((float*)Cptr)[(size_t)row * N + col] = val;
        }
      }
    }
  }
}

// ---------------- classifier (both regions in one launch) ----------------

__global__ __launch_bounds__(256) void cls_kernel(const uint* __restrict__ t3,
                                                  const float* __restrict__ Wc1,
                                                  const float* __restrict__ bc1,
                                                  const float* __restrict__ Wc2,
                                                  const float* __restrict__ bc2,
                                                  float* __restrict__ out1,
                                                  float* __restrict__ out2) {
  int half = gridDim.x >> 1;
  int region = blockIdx.x >= half;
  int bid = region ? blockIdx.x - half : blockIdx.x;
  const float* Wc = region ? Wc2 : Wc1;
  const float* bc = region ? bc2 : bc1;
  float* outp = region ? out2 : out1;
  int row0 = region ? TEXT_CNT : 0;
  int nrows = region ? (N_NODES - TEXT_CNT) : TEXT_CNT;

  int lane = threadIdx.x & 63;
  int wav = bid * 4 + (threadIdx.x >> 6);
  int nw = half * 4;
  int c = lane & 15;
  int kg = lane >> 4;
  float w[32];
#pragma unroll
  for (int j = 0; j < 32; ++j) w[j] = Wc[(kg * 32 + j) * NCLASS + c];
  float bcv = bc[c];
  for (int r = wav; r < nrows; r += nw) {
    const uint4* rp = (const uint4*)&t3[(size_t)(row0 + r) * 64 + kg * 16];
    float acc = 0.f;
#pragma unroll
    for (int q = 0; q < 4; ++q) {
      uint4 u = rp[q];
      acc += bf_lo(u.x) * w[q * 8 + 0] + bf_hi(u.x) * w[q * 8 + 1]
           + bf_lo(u.y) * w[q * 8 + 2] + bf_hi(u.y) * w[q * 8 + 3]
           + bf_lo(u.z) * w[q * 8 + 4] + bf_hi(u.z) * w[q * 8 + 5]
           + bf_lo(u.w) * w[q * 8 + 6] + bf_hi(u.w) * w[q * 8 + 7];
    }
    acc += __shfl_xor(acc, 16);
    acc += __shfl_xor(acc, 32);
    if (lane < 16) outp[(size_t)r * NCLASS + lane] = acc + bcv;
  }
}

// ---------------- launch ----------------

extern "C" void kernel_launch(void* const* d_in, const int* in_sizes, int n_in,
                              void* d_out, int out_size, void* d_ws, size_t ws_size,
                              hipStream_t stream) {
  const float* x     = (const float*)d_in[0];
  const int*   arows = (const int*)d_in[1];
  const int*   acols = (const int*)d_in[2];
  const float* avals = (const float*)d_in[3];
  const float* W1    = (const float*)d_in[4];
  const float* b1    = (const float*)d_in[5];
  const float* W2    = (const float*)d_in[6];
  const float* b2    = (const float*)d_in[7];
  const float* cW1   = (const float*)d_in[8];
  const float* cb1   = (const float*)d_in[9];
  const float* cW2   = (const float*)d_in[10];
  const float* cb2   = (const float*)d_in[11];
  float* outp = (float*)d_out;

  char* ws = (char*)d_ws;
  size_t off = 0;
  auto alloc = [&](size_t bytes) -> void* {
    void* p = ws + off;
    off += (bytes + 255) & ~(size_t)255;
    return p;
  };
  uint*  t1u     = (uint*) alloc((size_t)N_NODES * 64 * 4);   // bf16 [N][128]
  uint*  hu      = (uint*) alloc((size_t)N_NODES * 64 * 4);   // bf16 [N][128]
  uint*  t3u     = (uint*) alloc((size_t)N_NODES * 64 * 4);   // bf16 [N][128]
  int2*  packedA = (int2*) alloc((size_t)NB * CAP * 8);       // fixed-cap buckets
  int2*  packedB = (int2*) alloc((size_t)N_EDGES * 8);        // row-grouped (CSR)
  int*   bbase   = (int*)  alloc((size_t)(NB + 1) * 4);
  int*   gcursor = (int*)  alloc((size_t)NB * 4);
  int*   rowp    = (int*)  alloc((size_t)(N_NODES + 1) * 4);
  unsigned short* W1t = (unsigned short*)alloc((size_t)NHID * NFEAT * 2);  // [128][256]
  unsigned short* W2t = (unsigned short*)alloc((size_t)NFEAT * NHID * 2);  // [256][128]
  float* Wc1     = (float*)alloc(NHID * NCLASS * 4);
  float* Wc2     = (float*)alloc(NHID * NCLASS * 4);
  float* bc1     = (float*)alloc(64);
  float* bc2     = (float*)alloc(64);

  // ---- 1. fused prep (weights + cursors) ----
  prep_kernel<<<(69632 + NB + 255) / 256, 256, 0, stream>>>(
      W1, W2, b2, cW1, cb1, cW2, cb2, W1t, W2t, Wc1, bc1, Wc2, bc2, gcursor);

  // ---- 2. bucket scatter ----
  bucket_scatter_kernel<<<NBLKS, 256, 0, stream>>>(arows, acols, avals, gcursor, packedA, N_EDGES);

  // ---- 3-4. scan + finalize ----
  bucket_scan_kernel<<<1, 512, 0, stream>>>(gcursor, bbase);
  csr_finalize_kernel<<<NB, 512, 0, stream>>>(bbase, packedA, packedB, rowp);

  // ---- 5. t1 = bf16(x @ W1) ----
  int mblk = (N_NODES + 127) / 128;  // 782
  gemm_mfma_kernel<1, 1, NFEAT, NHID><<<dim3(mblk, 1), 256, 0, stream>>>(
      x, (const __bf16*)W1t, nullptr, t1u, N_NODES);
  // ---- 6. h = bf16(relu(A @ t1 + b1)) ----
  spmm_bf16_kernel<<<(N_NODES + 3) / 4, 256, 0, stream>>>(rowp, packedB, t1u, hu, b1, 1, N_NODES);
  // ---- 7. t3 = bf16(A @ h) ----
  spmm_bf16_kernel<<<(N_NODES + 3) / 4, 256, 0, stream>>>(rowp, packedB, hu, t3u, nullptr, 0, N_NODES);
  // ---- 8. out = t3 @ W2 + b2 (fp32 out) ----
  gemm_mfma_kernel<0, 0, NHID, NFEAT><<<dim3(mblk, 2), 256, 0, stream>>>(
      t3u, (const __bf16*)W2t, b2, outp, N_NODES);
  // ---- 9. classifiers ----
  cls_kernel<<<2048, 256, 0, stream>>>(t3u, Wc1, bc1, Wc2, bc2,
      outp + (size_t)N_NODES * NFEAT,
      outp + (size_t)N_NODES * NFEAT + (size_t)TEXT_CNT * NCLASS);
}

// Round 9
// 445.225 us; speedup vs baseline: 1.1512x; 1.0757x over previous
//
#include <hip/hip_runtime.h>

#define N_NODES  100000
#define N_EDGES  3200000
#define NFEAT    256
#define NHID     128
#define NCLASS   16
#define TEXT_CNT 50000

#define RPB      256                          // rows per bucket
#define NB       ((N_NODES + RPB - 1) / RPB)  // 391 buckets
#define CAP      16384                        // fixed bucket capacity (2^14)
#define S_EPT    32                           // edges/thread, scatter pass
#define NBLKS    ((N_EDGES + 256 * S_EPT - 1) / (256 * S_EPT))  // 391
#define GEMM_LDS (2 * 128 * 40 * 2)           // 20480 B dynamic-LDS union

typedef unsigned int uint;
typedef __bf16 bf16x8 __attribute__((ext_vector_type(8)));
typedef __bf16 bf16x4 __attribute__((ext_vector_type(4)));
typedef float f32x4 __attribute__((ext_vector_type(4)));

__device__ inline uint bf16_rne(float f) {
  uint u = __float_as_uint(f);
  return (u + 0x7fffu + ((u >> 16) & 1u)) >> 16;
}
__device__ inline float bf_lo(uint u) { return __uint_as_float(u << 16); }
__device__ inline float bf_hi(uint u) { return __uint_as_float(u & 0xffff0000u); }

// ---------------- fused prep: W1t, W2t, Wc1/2, bc1/2, cursor init ----------------

__global__ __launch_bounds__(256) void prep_kernel(const float* __restrict__ W1,
                                                   const float* __restrict__ W2,
                                                   const float* __restrict__ b2,
                                                   const float* __restrict__ cW1,
                                                   const float* __restrict__ cb1,
                                                   const float* __restrict__ cW2,
                                                   const float* __restrict__ cb2,
                                                   unsigned short* __restrict__ W1t,
                                                   unsigned short* __restrict__ W2t,
                                                   float* __restrict__ Wc1, float* __restrict__ bc1,
                                                   float* __restrict__ Wc2, float* __restrict__ bc2,
                                                   int* __restrict__ gcursor) {
  int idx = blockIdx.x * 256 + threadIdx.x;
  if (idx < 32768) {                       // W1t[n][k] = bf16(W1[k][n]), K=256,N=128
    int n = idx >> 8, k = idx & 255;
    W1t[idx] = (unsigned short)bf16_rne(W1[(size_t)k * NHID + n]);
  } else if (idx < 65536) {                // W2t[n][k] = bf16(W2[k][n]), K=128,N=256
    int i2 = idx - 32768;
    int n = i2 >> 7, k = i2 & 127;
    W2t[i2] = (unsigned short)bf16_rne(W2[(size_t)k * NFEAT + n]);
  } else if (idx < 69632) {                // Wc = W2 @ cW
    int e = idx - 65536;
    int set = e >> 11;
    int e2 = e & 2047;
    int i = e2 >> 4, c = e2 & 15;
    const float* cw = set ? cW2 : cW1;
    float acc = 0.f;
    for (int k = 0; k < NFEAT; ++k)
      acc += W2[(size_t)i * NFEAT + k] * cw[k * NCLASS + c];
    (set ? Wc2 : Wc1)[e2] = acc;
    if (e < 32) {
      int s2 = e >> 4, c2 = e & 15;
      const float* cwb = s2 ? cW2 : cW1;
      float b = (s2 ? cb2 : cb1)[c2];
      for (int k = 0; k < NFEAT; ++k) b += b2[k] * cwb[k * NCLASS + c2];
      (s2 ? bc2 : bc1)[c2] = b;
    }
  } else if (idx < 69632 + NB) {           // gcursor[b] = b*CAP
    int b = idx - 69632;
    gcursor[b] = b * CAP;
  }
}

// ---------------- scatter body (uses 3128 B of the dynamic-LDS union) ----------------
// packedA[p] = { (rowlocal<<17) | col , float_bits(val) }

__device__ __forceinline__ void scatter_body(int bx, const int* __restrict__ rows,
                                             const int* __restrict__ cols,
                                             const float* __restrict__ vals,
                                             int* __restrict__ gcursor,
                                             int2* __restrict__ packed, int E,
                                             int* __restrict__ smem) {
  int* hist = smem;          // [NB]
  int* cur = smem + NB;      // [NB]
  for (int i = threadIdx.x; i < NB; i += 256) hist[i] = 0;
  __syncthreads();
  int base = bx * (256 * S_EPT);
#pragma unroll
  for (int i = 0; i < S_EPT; ++i) {
    int e = base + i * 256 + threadIdx.x;
    if (e < E) atomicAdd(&hist[rows[e] >> 8], 1);
  }
  __syncthreads();
  for (int i = threadIdx.x; i < NB; i += 256) {
    int h = hist[i];
    cur[i] = h ? atomicAdd(&gcursor[i], h) : 0;
  }
  __syncthreads();
#pragma unroll
  for (int i = 0; i < S_EPT; ++i) {
    int e = base + i * 256 + threadIdx.x;
    if (e < E) {
      int r = rows[e];
      int b = r >> 8;
      int p = atomicAdd(&cur[b], 1);
      if (p < ((b + 1) << 14))   // capacity guard
        packed[p] = make_int2(((r & 255) << 17) | cols[e], __float_as_int(vals[e]));
    }
  }
}

// ---------------- bf16 MFMA GEMM body (uses 20480 B of the dynamic-LDS union) ----------------
// 128x128 tile, BK=32, 256 threads = 4 waves (2x2), 4x4 16x16x32 frags/wave.

template <int A_FP32, int OUT_BF16, int K, int N>
__device__ __forceinline__ void gemm_body(int bx, int by, const void* __restrict__ Aptr,
                                          const __bf16* __restrict__ Bt,
                                          const float* __restrict__ bias,
                                          void* __restrict__ Cptr, int M,
                                          __bf16* __restrict__ As, __bf16* __restrict__ Bs) {
  int tid = threadIdx.x;
  int lane = tid & 63;
  int w = tid >> 6;
  int wr = w >> 1, wc = w & 1;
  int brow = bx * 128;
  int bcol = by * 128;
  int r16 = lane & 15, kb = lane >> 4;

  f32x4 acc[4][4];
#pragma unroll
  for (int m = 0; m < 4; ++m)
#pragma unroll
    for (int n = 0; n < 4; ++n) acc[m][n] = (f32x4){0.f, 0.f, 0.f, 0.f};

  for (int k0 = 0; k0 < K; k0 += 32) {
    if (A_FP32) {
      const float* A = (const float*)Aptr;
#pragma unroll
      for (int i = 0; i < 4; ++i) {
        int idx = tid + i * 256;
        int row = idx >> 3;
        int kq = (idx & 7) << 2;
        int gr = brow + row;
        float4 v = make_float4(0.f, 0.f, 0.f, 0.f);
        if (gr < M) v = *(const float4*)&A[(size_t)gr * K + k0 + kq];
        bf16x4 o;
        o[0] = (__bf16)v.x; o[1] = (__bf16)v.y; o[2] = (__bf16)v.z; o[3] = (__bf16)v.w;
        *(bf16x4*)&As[row * 40 + kq] = o;
      }
    } else {
      const __bf16* A = (const __bf16*)Aptr;
#pragma unroll
      for (int i = 0; i < 2; ++i) {
        int idx = tid + i * 256;
        int row = idx >> 2;
        int kq = (idx & 3) << 3;
        int gr = brow + row;
        bf16x8 v = {};
        if (gr < M) v = *(const bf16x8*)&A[(size_t)gr * K + k0 + kq];
        *(bf16x8*)&As[row * 40 + kq] = v;
      }
    }
#pragma unroll
    for (int i = 0; i < 2; ++i) {
      int idx = tid + i * 256;
      int col = idx >> 2;
      int kq = (idx & 3) << 3;
      bf16x8 v = *(const bf16x8*)&Bt[(size_t)(bcol + col) * K + k0 + kq];
      *(bf16x8*)&Bs[col * 40 + kq] = v;
    }
    __syncthreads();

    bf16x8 a[4], b[4];
#pragma unroll
    for (int m = 0; m < 4; ++m)
      a[m] = *(bf16x8*)&As[(wr * 64 + m * 16 + r16) * 40 + kb * 8];
#pragma unroll
    for (int n = 0; n < 4; ++n)
      b[n] = *(bf16x8*)&Bs[(wc * 64 + n * 16 + r16) * 40 + kb * 8];
#pragma unroll
    for (int m = 0; m < 4; ++m)
#pragma unroll
      for (int n = 0; n < 4; ++n)
        acc[m][n] = __builtin_amdgcn_mfma_f32_16x16x32_bf16(a[m], b[n], acc[m][n], 0, 0, 0);
    __syncthreads();
  }

  int crow0 = brow + wr * 64;
  int ccol0 = bcol + wc * 64;
#pragma unroll
  for (int n = 0; n < 4; ++n) {
    int col = ccol0 + n * 16 + r16;
    float bv = bias ? bias[col] : 0.f;
#pragma unroll
    for (int m = 0; m < 4; ++m) {
#pragma unroll
      for (int r = 0; r < 4; ++r) {
        int row = crow0 + m * 16 + kb * 4 + r;
        if (row < M) {
          float val = acc[m][n][r] + bv;
          if (OUT_BF16)
            ((unsigned short*)Cptr)[(size_t)row * N + col] = (unsigned short)bf16_rne(val);
          else
            ((float*)Cptr)[(size_t)row * N + col] = val;
        }
      }
    }
  }
}

// ---------------- fused: scatter (blocks [0,NBLKS)) + gemm1 (rest), dynamic-LDS union ----------------

__global__ __launch_bounds__(256) void fused_sg1_kernel(
    const int* __restrict__ rows, const int* __restrict__ cols, const float* __restrict__ vals,
    int* __restrict__ gcursor, int2* __restrict__ packedA, int E,
    const float* __restrict__ x, const __bf16* __restrict__ W1t, uint* __restrict__ t1u, int M) {
  extern __shared__ __align__(16) char dynbuf[];
  if (blockIdx.x < NBLKS)
    scatter_body(blockIdx.x, rows, cols, vals, gcursor, packedA, E, (int*)dynbuf);
  else
    gemm_body<1, 1, NFEAT, NHID>(blockIdx.x - NBLKS, 0, x, W1t, nullptr, t1u, M,
                                 (__bf16*)dynbuf, (__bf16*)dynbuf + 128 * 40);
}

// ---------------- per-bucket CSR finalize with integrated scan (512 threads) ----------------
// packedB[p] = { col<<8 (byte offset of feature row), float_bits(val) }

__global__ __launch_bounds__(512) void csr_finalize_kernel(const int* __restrict__ gcursor,
                                                           const int2* __restrict__ packed_in,
                                                           int2* __restrict__ packed_out,
                                                           int* __restrict__ row_ptr) {
  __shared__ int pre[512];
  __shared__ int hist[RPB];
  __shared__ int cur[RPB];
  int b = blockIdx.x;
  int t = threadIdx.x;
  // integrated scan of bucket counts -> this bucket's global CSR base
  int cntt = (t < NB) ? (gcursor[t] - t * CAP) : 0;
  pre[t] = cntt;
  __syncthreads();
  for (int off = 1; off < 512; off <<= 1) {
    int u = (t >= off) ? pre[t - off] : 0;
    __syncthreads();
    pre[t] += u;
    __syncthreads();
  }
  int cnt = gcursor[b] - b * CAP;
  int gout = pre[b] - cnt;                 // exclusive prefix
  int s0 = b * CAP;
  int end = s0 + cnt;
  if (t < RPB) hist[t] = 0;
  __syncthreads();
  {
    int i = s0 + t;
    for (; i + 1536 < end; i += 2048) {
      int2 a0 = packed_in[i], a1 = packed_in[i + 512];
      int2 a2 = packed_in[i + 1024], a3 = packed_in[i + 1536];
      atomicAdd(&hist[a0.x >> 17], 1);
      atomicAdd(&hist[a1.x >> 17], 1);
      atomicAdd(&hist[a2.x >> 17], 1);
      atomicAdd(&hist[a3.x >> 17], 1);
    }
    for (; i < end; i += 512) atomicAdd(&hist[packed_in[i].x >> 17], 1);
  }
  __syncthreads();
  int v = (t < RPB) ? hist[t] : 0;
  if (t < RPB) cur[t] = v;
  __syncthreads();
  for (int off = 1; off < RPB; off <<= 1) {
    int u = (t >= off && t < RPB) ? cur[t - off] : 0;
    __syncthreads();
    if (t < RPB) cur[t] += u;
    __syncthreads();
  }
  if (t < RPB) {
    int rbase = gout + cur[t] - v;
    int row = b * RPB + t;
    if (row < N_NODES) row_ptr[row] = rbase;
    cur[t] = rbase;
  }
  if (b == 0 && t == 0) row_ptr[N_NODES] = N_EDGES;
  __syncthreads();
  {
    int i = s0 + t;
    for (; i + 1536 < end; i += 2048) {
      int2 a0 = packed_in[i], a1 = packed_in[i + 512];
      int2 a2 = packed_in[i + 1024], a3 = packed_in[i + 1536];
      int p0 = atomicAdd(&cur[a0.x >> 17], 1);
      int p1 = atomicAdd(&cur[a1.x >> 17], 1);
      int p2 = atomicAdd(&cur[a2.x >> 17], 1);
      int p3 = atomicAdd(&cur[a3.x >> 17], 1);
      packed_out[p0] = make_int2((a0.x & 0x1FFFF) << 8, a0.y);
      packed_out[p1] = make_int2((a1.x & 0x1FFFF) << 8, a1.y);
      packed_out[p2] = make_int2((a2.x & 0x1FFFF) << 8, a2.y);
      packed_out[p3] = make_int2((a3.x & 0x1FFFF) << 8, a3.y);
    }
    for (; i < end; i += 512) {
      int2 pk = packed_in[i];
      int p = atomicAdd(&cur[pk.x >> 17], 1);
      packed_out[p] = make_int2((pk.x & 0x1FFFF) << 8, pk.y);
    }
  }
}

// ---------------- CSR SpMM over bf16 features, wave per row, 8B/lane pair-loads ----------------

__global__ __launch_bounds__(256) void spmm_bf16_kernel(const int* __restrict__ row_ptr,
                                                        const int2* __restrict__ packed,
                                                        const uint* __restrict__ src,   // [n][64] dwords
                                                        uint* __restrict__ dst,         // [n][64] dwords
                                                        const float* __restrict__ bias,
                                                        int relu, int nrows) {
  int tid = threadIdx.x;
  int lane = tid & 63;
  int half = lane >> 5;
  int l32 = lane & 31;
  int row = blockIdx.x * 4 + (tid >> 6);
  if (row >= nrows) return;
  int s = row_ptr[row];
  int e = row_ptr[row + 1];
  const char* srcb = (const char*)src + (l32 << 3);
  float a0 = 0.f, a1 = 0.f, a2 = 0.f, a3 = 0.f;
  int i = s;
  for (; i + 16 <= e; i += 16) {
    int2 m0 = packed[i + 0 + half], m1 = packed[i + 2 + half];
    int2 m2 = packed[i + 4 + half], m3 = packed[i + 6 + half];
    int2 m4 = packed[i + 8 + half], m5 = packed[i + 10 + half];
    int2 m6 = packed[i + 12 + half], m7 = packed[i + 14 + half];
    uint2 u0 = *(const uint2*)(srcb + (uint)m0.x);
    uint2 u1 = *(const uint2*)(srcb + (uint)m1.x);
    uint2 u2 = *(const uint2*)(srcb + (uint)m2.x);
    uint2 u3 = *(const uint2*)(srcb + (uint)m3.x);
    uint2 u4 = *(const uint2*)(srcb + (uint)m4.x);
    uint2 u5 = *(const uint2*)(srcb + (uint)m5.x);
    uint2 u6 = *(const uint2*)(srcb + (uint)m6.x);
    uint2 u7 = *(const uint2*)(srcb + (uint)m7.x);
    float v0 = __int_as_float(m0.y), v1 = __int_as_float(m1.y);
    float v2 = __int_as_float(m2.y), v3 = __int_as_float(m3.y);
    float v4 = __int_as_float(m4.y), v5 = __int_as_float(m5.y);
    float v6 = __int_as_float(m6.y), v7 = __int_as_float(m7.y);
    a0 += v0 * bf_lo(u0.x); a1 += v0 * bf_hi(u0.x); a2 += v0 * bf_lo(u0.y); a3 += v0 * bf_hi(u0.y);
    a0 += v1 * bf_lo(u1.x); a1 += v1 * bf_hi(u1.x); a2 += v1 * bf_lo(u1.y); a3 += v1 * bf_hi(u1.y);
    a0 += v2 * bf_lo(u2.x); a1 += v2 * bf_hi(u2.x); a2 += v2 * bf_lo(u2.y); a3 += v2 * bf_hi(u2.y);
    a0 += v3 * bf_lo(u3.x); a1 += v3 * bf_hi(u3.x); a2 += v3 * bf_lo(u3.y); a3 += v3 * bf_hi(u3.y);
    a0 += v4 * bf_lo(u4.x); a1 += v4 * bf_hi(u4.x); a2 += v4 * bf_lo(u4.y); a3 += v4 * bf_hi(u4.y);
    a0 += v5 * bf_lo(u5.x); a1 += v5 * bf_hi(u5.x); a2 += v5 * bf_lo(u5.y); a3 += v5 * bf_hi(u5.y);
    a0 += v6 * bf_lo(u6.x); a1 += v6 * bf_hi(u6.x); a2 += v6 * bf_lo(u6.y); a3 += v6 * bf_hi(u6.y);
    a0 += v7 * bf_lo(u7.x); a1 += v7 * bf_hi(u7.x); a2 += v7 * bf_lo(u7.y); a3 += v7 * bf_hi(u7.y);
  }
  for (; i + 8 <= e; i += 8) {
    int2 m0 = packed[i + 0 + half], m1 = packed[i + 2 + half];
    int2 m2 = packed[i + 4 + half], m3 = packed[i + 6 + half];
    uint2 u0 = *(const uint2*)(srcb + (uint)m0.x);
    uint2 u1 = *(const uint2*)(srcb + (uint)m1.x);
    uint2 u2 = *(const uint2*)(srcb + (uint)m2.x);
    uint2 u3 = *(const uint2*)(srcb + (uint)m3.x);
    float v0 = __int_as_float(m0.y), v1 = __int_as_float(m1.y);
    float v2 = __int_as_float(m2.y), v3 = __int_as_float(m3.y);
    a0 += v0 * bf_lo(u0.x); a1 += v0 * bf_hi(u0.x); a2 += v0 * bf_lo(u0.y); a3 += v0 * bf_hi(u0.y);
    a0 += v1 * bf_lo(u1.x); a1 += v1 * bf_hi(u1.x); a2 += v1 * bf_lo(u1.y); a3 += v1 * bf_hi(u1.y);
    a0 += v2 * bf_lo(u2.x); a1 += v2 * bf_hi(u2.x); a2 += v2 * bf_lo(u2.y); a3 += v2 * bf_hi(u2.y);
    a0 += v3 * bf_lo(u3.x); a1 += v3 * bf_hi(u3.x); a2 += v3 * bf_lo(u3.y); a3 += v3 * bf_hi(u3.y);
  }
  for (; i + 4 <= e; i += 4) {
    int2 m0 = packed[i + 0 + half], m1 = packed[i + 2 + half];
    uint2 u0 = *(const uint2*)(srcb + (uint)m0.x);
    uint2 u1 = *(const uint2*)(srcb + (uint)m1.x);
    float v0 = __int_as_float(m0.y), v1 = __int_as_float(m1.y);
    a0 += v0 * bf_lo(u0.x); a1 += v0 * bf_hi(u0.x); a2 += v0 * bf_lo(u0.y); a3 += v0 * bf_hi(u0.y);
    a0 += v1 * bf_lo(u1.x); a1 += v1 * bf_hi(u1.x); a2 += v1 * bf_lo(u1.y); a3 += v1 * bf_hi(u1.y);
  }
  for (; i < e; i += 2) {
    int ee = i + half;
    int ok = ee < e;
    int2 m = packed[ok ? ee : (e - 1)];
    uint2 u = *(const uint2*)(srcb + (uint)m.x);
    float v = ok ? __int_as_float(m.y) : 0.f;
    a0 += v * bf_lo(u.x); a1 += v * bf_hi(u.x); a2 += v * bf_lo(u.y); a3 += v * bf_hi(u.y);
  }
  a0 += __shfl_xor(a0, 32); a1 += __shfl_xor(a1, 32);
  a2 += __shfl_xor(a2, 32); a3 += __shfl_xor(a3, 32);
  if (half == 0) {
    if (bias) {
      a0 += bias[4 * l32 + 0]; a1 += bias[4 * l32 + 1];
      a2 += bias[4 * l32 + 2]; a3 += bias[4 * l32 + 3];
    }
    if (relu) {
      a0 = fmaxf(a0, 0.f); a1 = fmaxf(a1, 0.f);
      a2 = fmaxf(a2, 0.f); a3 = fmaxf(a3, 0.f);
    }
    uint2 o;
    o.x = bf16_rne(a0) | (bf16_rne(a1) << 16);
    o.y = bf16_rne(a2) | (bf16_rne(a3) << 16);
    *(uint2*)&dst[(size_t)row * 64 + l32 * 2] = o;
  }
}

// ---------------- standalone GEMM kernel (for gemm2) ----------------

template <int A_FP32, int OUT_BF16, int K, int N>
__global__ __launch_bounds__(256) void gemm_mfma_kernel(const void* __restrict__ Aptr,
                                                        const __bf16* __restrict__ Bt,
                                                        const float* __restrict__ bias,
                                                        void* __restrict__ Cptr, int M) {
  __shared__ __align__(16) __bf16 smem[2 * 128 * 40];
  gemm_body<A_FP32, OUT_BF16, K, N>(blockIdx.x, blockIdx.y, Aptr, Bt, bias, Cptr, M,
                                    smem, smem + 128 * 40);
}

// ---------------- classifier (both regions in one launch) ----------------

__global__ __launch_bounds__(256) void cls_kernel(const uint* __restrict__ t3,
                                                  const float* __restrict__ Wc1,
                                                  const float* __restrict__ bc1,
                                                  const float* __restrict__ Wc2,
                                                  const float* __restrict__ bc2,
                                                  float* __restrict__ out1,
                                                  float* __restrict__ out2) {
  int half = gridDim.x >> 1;
  int region = blockIdx.x >= half;
  int bid = region ? blockIdx.x - half : blockIdx.x;
  const float* Wc = region ? Wc2 : Wc1;
  const float* bc = region ? bc2 : bc1;
  float* outp = region ? out2 : out1;
  int row0 = region ? TEXT_CNT : 0;
  int nrows = region ? (N_NODES - TEXT_CNT) : TEXT_CNT;

  int lane = threadIdx.x & 63;
  int wav = bid * 4 + (threadIdx.x >> 6);
  int nw = half * 4;
  int c = lane & 15;
  int kg = lane >> 4;
  float w[32];
#pragma unroll
  for (int j = 0; j < 32; ++j) w[j] = Wc[(kg * 32 + j) * NCLASS + c];
  float bcv = bc[c];
  for (int r = wav; r < nrows; r += nw) {
    const uint4* rp = (const uint4*)&t3[(size_t)(row0 + r) * 64 + kg * 16];
    float acc = 0.f;
#pragma unroll
    for (int q = 0; q < 4; ++q) {
      uint4 u = rp[q];
      acc += bf_lo(u.x) * w[q * 8 + 0] + bf_hi(u.x) * w[q * 8 + 1]
           + bf_lo(u.y) * w[q * 8 + 2] + bf_hi(u.y) * w[q * 8 + 3]
           + bf_lo(u.z) * w[q * 8 + 4] + bf_hi(u.z) * w[q * 8 + 5]
           + bf_lo(u.w) * w[q * 8 + 6] + bf_hi(u.w) * w[q * 8 + 7];
    }
    acc += __shfl_xor(acc, 16);
    acc += __shfl_xor(acc, 32);
    if (lane < 16) outp[(size_t)r * NCLASS + lane] = acc + bcv;
  }
}

// ---------------- launch ----------------

extern "C" void kernel_launch(void* const* d_in, const int* in_sizes, int n_in,
                              void* d_out, int out_size, void* d_ws, size_t ws_size,
                              hipStream_t stream) {
  const float* x     = (const float*)d_in[0];
  const int*   arows = (const int*)d_in[1];
  const int*   acols = (const int*)d_in[2];
  const float* avals = (const float*)d_in[3];
  const float* W1    = (const float*)d_in[4];
  const float* b1    = (const float*)d_in[5];
  const float* W2    = (const float*)d_in[6];
  const float* b2    = (const float*)d_in[7];
  const float* cW1   = (const float*)d_in[8];
  const float* cb1   = (const float*)d_in[9];
  const float* cW2   = (const float*)d_in[10];
  const float* cb2   = (const float*)d_in[11];
  float* outp = (float*)d_out;

  char* ws = (char*)d_ws;
  size_t off = 0;
  auto alloc = [&](size_t bytes) -> void* {
    void* p = ws + off;
    off += (bytes + 255) & ~(size_t)255;
    return p;
  };
  uint*  t1u     = (uint*) alloc((size_t)N_NODES * 64 * 4);   // bf16 [N][128]
  uint*  hu      = (uint*) alloc((size_t)N_NODES * 64 * 4);   // bf16 [N][128]
  uint*  t3u     = (uint*) alloc((size_t)N_NODES * 64 * 4);   // bf16 [N][128]
  int2*  packedA = (int2*) alloc((size_t)NB * CAP * 8);       // fixed-cap buckets
  int2*  packedB = (int2*) alloc((size_t)N_EDGES * 8);        // row-grouped (CSR)
  int*   gcursor = (int*)  alloc((size_t)NB * 4);
  int*   rowp    = (int*)  alloc((size_t)(N_NODES + 1) * 4);
  unsigned short* W1t = (unsigned short*)alloc((size_t)NHID * NFEAT * 2);  // [128][256]
  unsigned short* W2t = (unsigned short*)alloc((size_t)NFEAT * NHID * 2);  // [256][128]
  float* Wc1     = (float*)alloc(NHID * NCLASS * 4);
  float* Wc2     = (float*)alloc(NHID * NCLASS * 4);
  float* bc1     = (float*)alloc(64);
  float* bc2     = (float*)alloc(64);

  // ---- 1. fused prep (weights + cursors) ----
  prep_kernel<<<(69632 + NB + 255) / 256, 256, 0, stream>>>(
      W1, W2, b2, cW1, cb1, cW2, cb2, W1t, W2t, Wc1, bc1, Wc2, bc2, gcursor);

  // ---- 2. fused: bucket scatter + t1 = bf16(x @ W1), dynamic-LDS union ----
  int mblk = (N_NODES + 127) / 128;  // 782
  fused_sg1_kernel<<<NBLKS + mblk, 256, GEMM_LDS, stream>>>(
      arows, acols, avals, gcursor, packedA, N_EDGES,
      x, (const __bf16*)W1t, t1u, N_NODES);

  // ---- 3. finalize (with integrated scan) ----
  csr_finalize_kernel<<<NB, 512, 0, stream>>>(gcursor, packedA, packedB, rowp);

  // ---- 4. h = bf16(relu(A @ t1 + b1)) ----
  spmm_bf16_kernel<<<(N_NODES + 3) / 4, 256, 0, stream>>>(rowp, packedB, t1u, hu, b1, 1, N_NODES);
  // ---- 5. t3 = bf16(A @ h) ----
  spmm_bf16_kernel<<<(N_NODES + 3) / 4, 256, 0, stream>>>(rowp, packedB, hu, t3u, nullptr, 0, N_NODES);
  // ---- 6. out = t3 @ W2 + b2 (fp32 out) ----
  gemm_mfma_kernel<0, 0, NHID, NFEAT><<<dim3(mblk, 2), 256, 0, stream>>>(
      t3u, (const __bf16*)W2t, b2, outp, N_NODES);
  // ---- 7. classifiers ----
  cls_kernel<<<2048, 256, 0, stream>>>(t3u, Wc1, bc1, Wc2, bc2,
      outp + (size_t)N_NODES * NFEAT,
      outp + (size_t)N_NODES * NFEAT + (size_t)TEXT_CNT * NCLASS);
}